// Round 3
// baseline (307.035 us; speedup 1.0000x reference)
//
#include <hip/hip_runtime.h>

// PointPillarScatter on MI355X (gfx950)
// Layout constants fixed by the reference:
#define GNX 512
#define GNY 512
#define GC  64

// Step 0: fill cell->pillar map with -1 (plain kernel; hipMemsetAsync was
// suspect under graph capture, and this is only 4 MiB / ~2 us anyway).
__global__ void pp_fill_map(int* __restrict__ map, int n) {
    int i = blockIdx.x * blockDim.x + threadIdx.x;
    if (i < n) map[i] = -1;
}

// Step 1: scatter pillar index p into a dense (b, y, x) -> p map.
// coords rows: (b, z, y, x). NOTE: harness passes integer inputs as int32
// (NOT int64 — round 2's long long cast produced garbage indices and a
// device memory fault).
__global__ void pp_scatter_idx(const int* __restrict__ coords,
                               int* __restrict__ map, int P) {
    int p = blockIdx.x * blockDim.x + threadIdx.x;
    if (p >= P) return;
    int b = coords[4 * p + 0];
    int z = coords[4 * p + 1];
    int y = coords[4 * p + 2];
    int x = coords[4 * p + 3];
    int cell = b * (GNY * GNX) + z + y * GNX + x;
    map[cell] = p;
}

// Step 2: one thread per 4 consecutive output elements (channels-first layout
// [B, C, NY, NX], so 4 consecutive x). Fuses zero-fill + gather into one
// coalesced streaming write of the full 256 MiB output.
__global__ void pp_gather_out(const float* __restrict__ feat,
                              const int* __restrict__ map,
                              float4* __restrict__ out, int n4) {
    int tid = blockIdx.x * blockDim.x + threadIdx.x;
    if (tid >= n4) return;
    int e = tid << 2;                 // flat output element index (fits in int: 67M)
    int x    = e & (GNX - 1);
    int rest = e >> 9;                // (b*C + c)*NY + y
    int y    = rest & (GNY - 1);
    int bc   = rest >> 9;             // b*C + c
    int c    = bc & (GC - 1);
    int b    = bc >> 6;
    int cellbase = (b << 18) + (y << 9) + x;   // b*NY*NX + y*NX + x
    int4 m = *(const int4*)(map + cellbase);   // 16B aligned: x % 4 == 0
    float4 v;
    v.x = (m.x >= 0) ? feat[(m.x << 6) + c] : 0.0f;
    v.y = (m.y >= 0) ? feat[(m.y << 6) + c] : 0.0f;
    v.z = (m.z >= 0) ? feat[(m.z << 6) + c] : 0.0f;
    v.w = (m.w >= 0) ? feat[(m.w << 6) + c] : 0.0f;
    out[tid] = v;
}

extern "C" void kernel_launch(void* const* d_in, const int* in_sizes, int n_in,
                              void* d_out, int out_size, void* d_ws, size_t ws_size,
                              hipStream_t stream) {
    const float* feat   = (const float*)d_in[0];
    const int*   coords = (const int*)d_in[1];   // int32! (harness converts int64)
    // batch_size (d_in[2]) not needed on host: derive from out_size.
    int P = in_sizes[1] / 4;                       // 120000
    int B = out_size / (GC * GNY * GNX);           // 4
    int* map = (int*)d_ws;
    int mapN = B * GNY * GNX;                      // 1,048,576 ints (4 MiB)

    pp_fill_map<<<(mapN + 255) / 256, 256, 0, stream>>>(map, mapN);

    pp_scatter_idx<<<(P + 255) / 256, 256, 0, stream>>>(coords, map, P);

    int n4 = out_size / 4;                         // 16,777,216 float4 stores
    pp_gather_out<<<(n4 + 255) / 256, 256, 0, stream>>>(feat, map, (float4*)d_out, n4);
}

// Round 4
// 301.688 us; speedup vs baseline: 1.0177x; 1.0177x over previous
//
#include <hip/hip_runtime.h>

// PointPillarScatter on MI355X (gfx950)
#define GNX 512
#define GNY 512
#define GC  64

// component-by-static-index helper (folds at compile time under #pragma unroll)
#define COMP(v, t) ((t) == 0 ? (v).x : (t) == 1 ? (v).y : (t) == 2 ? (v).z : (v).w)

// Step 0: fill cell->pillar map with -1.
__global__ void pp_fill_map(int* __restrict__ map, int n) {
    int i = blockIdx.x * blockDim.x + threadIdx.x;
    if (i < n) map[i] = -1;
}

// Step 1: scatter pillar index p into dense (b, y, x) -> p map. coords int32.
__global__ void pp_scatter_idx(const int* __restrict__ coords,
                               int* __restrict__ map, int P) {
    int p = blockIdx.x * blockDim.x + threadIdx.x;
    if (p >= P) return;
    int b = coords[4 * p + 0];
    int z = coords[4 * p + 1];
    int y = coords[4 * p + 2];
    int x = coords[4 * p + 3];
    map[b * (GNY * GNX) + z + y * GNX + x] = p;
}

// Step 2: channel-blocked gather. Thread = (x-quad, 16-channel group).
// Reads int4 map once, then per occupied cell 4 consecutive float4 loads
// (one full 64B feat line, fully consumed -> no line-utilization waste).
// 16 float4 stores, each wave-contiguous within a channel plane.
__global__ void __launch_bounds__(256) pp_gather_out(
        const float* __restrict__ feat, const int* __restrict__ map,
        float* __restrict__ out, int nquad) {
    int q  = blockIdx.x * blockDim.x + threadIdx.x;   // x-quad id
    if (q >= nquad) return;
    int cg = blockIdx.y;                              // channel group 0..3

    int x4 = q & (GNX / 4 - 1);        // x / 4
    int y  = (q >> 7) & (GNY - 1);
    int b  = q >> 16;

    int cellbase = (b << 18) + (y << 9) + (x4 << 2);
    int4 m = *(const int4*)(map + cellbase);

    float4 fr[4][4];                   // [cell j][k] = channels cg*16+4k..+3
#pragma unroll
    for (int j = 0; j < 4; ++j)
#pragma unroll
        for (int k = 0; k < 4; ++k)
            fr[j][k] = make_float4(0.f, 0.f, 0.f, 0.f);

    {
        const int pj[4] = { m.x, m.y, m.z, m.w };
#pragma unroll
        for (int j = 0; j < 4; ++j) {
            if (pj[j] >= 0) {
                const float4* fp = (const float4*)(feat + (pj[j] << 6) + (cg << 4));
                fr[j][0] = fp[0];
                fr[j][1] = fp[1];
                fr[j][2] = fp[2];
                fr[j][3] = fp[3];
            }
        }
    }

    // store: channel w = 4k+t; out offset = ((b*64 + cg*16 + w) << 18) + y*512 + x4*4
    int rowoff = (y << 9) + (x4 << 2);
    float* obase = out + (((b << 6) + (cg << 4)) << 18) + rowoff;
#pragma unroll
    for (int k = 0; k < 4; ++k) {
#pragma unroll
        for (int t = 0; t < 4; ++t) {
            float4 v = make_float4(COMP(fr[0][k], t), COMP(fr[1][k], t),
                                   COMP(fr[2][k], t), COMP(fr[3][k], t));
            *(float4*)(obase + ((k * 4 + t) << 18)) = v;
        }
    }
}

extern "C" void kernel_launch(void* const* d_in, const int* in_sizes, int n_in,
                              void* d_out, int out_size, void* d_ws, size_t ws_size,
                              hipStream_t stream) {
    const float* feat   = (const float*)d_in[0];
    const int*   coords = (const int*)d_in[1];   // int32 (harness converts int64)
    int P = in_sizes[1] / 4;                     // 120000
    int B = out_size / (GC * GNY * GNX);         // 4
    int* map = (int*)d_ws;
    int mapN = B * GNY * GNX;                    // 1,048,576 ints (4 MiB)

    pp_fill_map<<<(mapN + 255) / 256, 256, 0, stream>>>(map, mapN);
    pp_scatter_idx<<<(P + 255) / 256, 256, 0, stream>>>(coords, map, P);

    int nquad = B * GNY * (GNX / 4);             // 262,144 x-quads
    dim3 grid((nquad + 255) / 256, GC / 16, 1);  // y-dim = 4 channel groups
    pp_gather_out<<<grid, 256, 0, stream>>>(feat, map, (float*)d_out, nquad);
}

// Round 5
// 294.324 us; speedup vs baseline: 1.0432x; 1.0250x over previous
//
#include <hip/hip_runtime.h>

// PointPillarScatter on MI355X (gfx950)
#define GNX 512
#define GNY 512
#define GC  64

typedef float vfloat4 __attribute__((ext_vector_type(4)));
typedef int   vint4   __attribute__((ext_vector_type(4)));

// Step 0: fill cell->pillar map with -1.
__global__ void pp_fill_map(int* __restrict__ map, int n) {
    int i = blockIdx.x * blockDim.x + threadIdx.x;
    if (i < n) map[i] = -1;
}

// Step 1: scatter pillar index p into dense (b, y, x) -> p map. coords int32.
__global__ void pp_scatter_idx(const int* __restrict__ coords,
                               int* __restrict__ map, int P) {
    int p = blockIdx.x * blockDim.x + threadIdx.x;
    if (p >= P) return;
    int b = coords[4 * p + 0];
    int z = coords[4 * p + 1];
    int y = coords[4 * p + 2];
    int x = coords[4 * p + 3];
    map[b * (GNY * GNX) + z + y * GNX + x] = p;
}

// Step 2: channel-blocked gather. Thread = (x-quad, 8-channel group).
// fr[4][2] = 32 VGPRs (vs 64 in R4) -> target 8 waves/SIMD for latency
// hiding of the map->feat dependent-load chain. Output stores are
// nontemporal: 268 MB pure stream should not evict map/feat from L2.
__global__ void __launch_bounds__(256) pp_gather_out(
        const float* __restrict__ feat, const int* __restrict__ map,
        float* __restrict__ out, int nquad) {
    int q  = blockIdx.x * blockDim.x + threadIdx.x;   // x-quad id
    if (q >= nquad) return;
    int cg = blockIdx.y;                              // channel group 0..7

    int x4 = q & (GNX / 4 - 1);        // x / 4
    int y  = (q >> 7) & (GNY - 1);
    int b  = q >> 16;

    int cellbase = (b << 18) + (y << 9) + (x4 << 2);
    vint4 m = *(const vint4*)(map + cellbase);

    vfloat4 fr[4][2];                  // [cell j][k] = channels cg*8+4k..+3
#pragma unroll
    for (int j = 0; j < 4; ++j) {
        fr[j][0] = (vfloat4)0.f;
        fr[j][1] = (vfloat4)0.f;
    }

#pragma unroll
    for (int j = 0; j < 4; ++j) {
        int pj = m[j];
        if (pj >= 0) {
            const vfloat4* fp = (const vfloat4*)(feat + (pj << 6) + (cg << 3));
            fr[j][0] = fp[0];
            fr[j][1] = fp[1];
        }
    }

    // store: channel w = 4k+t; plane stride 1<<18 floats
    int rowoff = (y << 9) + (x4 << 2);
    float* obase = out + (((b << 6) + (cg << 3)) << 18) + rowoff;
#pragma unroll
    for (int k = 0; k < 2; ++k) {
#pragma unroll
        for (int t = 0; t < 4; ++t) {
            vfloat4 v = { fr[0][k][t], fr[1][k][t], fr[2][k][t], fr[3][k][t] };
            __builtin_nontemporal_store(v, (vfloat4*)(obase + ((k * 4 + t) << 18)));
        }
    }
}

extern "C" void kernel_launch(void* const* d_in, const int* in_sizes, int n_in,
                              void* d_out, int out_size, void* d_ws, size_t ws_size,
                              hipStream_t stream) {
    const float* feat   = (const float*)d_in[0];
    const int*   coords = (const int*)d_in[1];   // int32 (harness converts int64)
    int P = in_sizes[1] / 4;                     // 120000
    int B = out_size / (GC * GNY * GNX);         // 4
    int* map = (int*)d_ws;
    int mapN = B * GNY * GNX;                    // 1,048,576 ints (4 MiB)

    pp_fill_map<<<(mapN + 255) / 256, 256, 0, stream>>>(map, mapN);
    pp_scatter_idx<<<(P + 255) / 256, 256, 0, stream>>>(coords, map, P);

    int nquad = B * GNY * (GNX / 4);             // 262,144 x-quads
    dim3 grid((nquad + 255) / 256, GC / 8, 1);   // y-dim = 8 channel groups
    pp_gather_out<<<grid, 256, 0, stream>>>(feat, map, (float*)d_out, nquad);
}